// Round 11
// baseline (152.577 us; speedup 1.0000x reference)
//
#include <hip/hip_runtime.h>

typedef __attribute__((ext_vector_type(4))) float f32x4;
typedef __attribute__((ext_vector_type(8))) short bf16x8;

#define D_MODEL 1024
#define NQK     2048
#define LSEQ    2048
#define NB      4
#define NX4     2097152   // 8192*1024/4
#define NW4     524288    // 2048*1024/4

__device__ inline unsigned short f2bf(float f) {
  unsigned u = __float_as_uint(f);
  unsigned r = (u + 0x7FFFu + ((u >> 16) & 1u)) >> 16;
  return (unsigned short)r;
}

__device__ inline void gl_lds16(const void* g, void* l) {
  __builtin_amdgcn_global_load_lds((const __attribute__((address_space(1))) void*)g,
                                   (__attribute__((address_space(3))) void*)l, 16, 0, 0);
}

// ---------------- fp32 -> bf16 convert (X then W) ----------------
__global__ __launch_bounds__(256) void cvt_kernel(
    const float4* __restrict__ X, const float4* __restrict__ W,
    ushort4* __restrict__ dst) {
  int i = blockIdx.x * 256 + threadIdx.x;
  float4 v = (i < NX4) ? X[i] : W[i - NX4];
  ushort4 o;
  o.x = f2bf(v.x); o.y = f2bf(v.y); o.z = f2bf(v.z); o.w = f2bf(v.w);
  dst[i] = o;
}

// ---------------- GEMM: Q,K = X W^T + bias, stored as fp8 e4m3 (unscaled) ----------------
__global__ __launch_bounds__(256) void gemm_qk(
    const unsigned short* __restrict__ Xb,   // [8192][1024] bf16
    const unsigned short* __restrict__ Wb,   // [2048][1024] bf16
    const float* __restrict__ bias,          // [3072]
    unsigned char* __restrict__ C)           // [8192][2048] fp8 e4m3
{
  __shared__ unsigned short As[128 * 32];  // 8KB
  __shared__ unsigned short Bs[128 * 32];  // 8KB
  int t = threadIdx.x;
  int w = t >> 6, lane = t & 63;
  int l15 = lane & 15, lg = lane >> 4;
  int bid = blockIdx.x;
  int k2 = bid >> 3, xcd = bid & 7;
  int m0 = (xcd * 8 + (k2 >> 4)) * 128;
  int n0 = (k2 & 15) * 128;
  int wm = (w >> 1) * 64, wn = (w & 1) * 64;
  f32x4 acc[4][4] = {};

  for (int kt = 0; kt < D_MODEL / 32; ++kt) {
#pragma unroll
    for (int i = 0; i < 2; ++i) {
      int ob = w * 1024 + i * 4096;
      int o = ob + lane * 16;
      int row = o >> 6;
      int kb = (o & 63) ^ (((row >> 1) & 3) << 4);
      gl_lds16(Xb + (m0 + row) * D_MODEL + kt * 32 + (kb >> 1), (char*)As + ob);
      gl_lds16(Wb + (n0 + row) * D_MODEL + kt * 32 + (kb >> 1), (char*)Bs + ob);
    }
    __syncthreads();
    bf16x8 a[4], b[4];
#pragma unroll
    for (int mi = 0; mi < 4; mi++) {
      int row = wm + mi * 16 + l15;
      int kb = (lg * 16) ^ (((row >> 1) & 3) << 4);
      a[mi] = *(const bf16x8*)((const char*)As + row * 64 + kb);
    }
#pragma unroll
    for (int ni = 0; ni < 4; ni++) {
      int row = wn + ni * 16 + l15;
      int kb = (lg * 16) ^ (((row >> 1) & 3) << 4);
      b[ni] = *(const bf16x8*)((const char*)Bs + row * 64 + kb);
    }
#pragma unroll
    for (int mi = 0; mi < 4; mi++)
#pragma unroll
      for (int ni = 0; ni < 4; ni++)
        acc[mi][ni] = __builtin_amdgcn_mfma_f32_16x16x32_bf16(a[mi], b[ni], acc[mi][ni], 0, 0, 0);
    __syncthreads();
  }

#pragma unroll
  for (int ni = 0; ni < 4; ni++) {
    int n = n0 + wn + ni * 16 + l15;
    float bv = bias[n];
#pragma unroll
    for (int mi = 0; mi < 4; mi++) {
      int mbase = m0 + wm + mi * 16 + lg * 4;
#pragma unroll
      for (int r = 0; r < 4; r++) {
        float v = acc[mi][ni][r] + bv;
        unsigned u = __builtin_amdgcn_cvt_pk_fp8_f32(v, v, 0, false);
        C[(size_t)(mbase + r) * NQK + n] = (unsigned char)u;
      }
    }
  }
}

// ---------------- fused attention column sums (fp8, wave-private strips) ----------------
// wg = 512 threads (8 waves), all sharing 32 q-rows of one (b,h); wave w owns key strip
// [w*256,(w+1)*256), staged 32-keys (8KB) at a time into a wave-private double-buffered
// 2x8KB LDS slice (128KB total => 1 wg/CU => 2 waves/EU => 256-VGPR budget, the proven
// no-spill regalloc regime: VGPR=96). Plain __launch_bounds__(512) — no waves/EU attr.
// Fully manually unrolled 8-tile pipeline, named E registers (rule #20), counted vmcnt(8).
// Column partials stored to a per-wg-private row of buf[256][8192] — NO atomics.
__global__ __launch_bounds__(512) void attn_fused(
    const unsigned char* __restrict__ C,   // [8192][2048] fp8
    float* __restrict__ buf)               // [256][8192] partial col sums
{
  __shared__ unsigned char Ks[131072];     // 8 waves x 2 bufs x 8KB
  int t = threadIdx.x;
  int w = t >> 6, lane = t & 63;
  int l15 = lane & 15, lg = lane >> 4;

  // XCD swizzle: 128 consecutive nids (2 bh) per XCD -> K slice L2-resident
  int nid = (blockIdx.x & 7) * 128 + (blockIdx.x >> 3);
  int bh = nid >> 6, rb = nid & 63;
  int b = bh >> 2, h = bh & 3;
  int hr = h * 64 + rb;                    // private partial row

  const unsigned char* Qbase = C + (size_t)(b * LSEQ + rb * 32) * NQK + h * 256;
  const unsigned char* Kbase = C + (size_t)(b * LSEQ + w * 256) * NQK + 1024 + h * 256;
  unsigned char* buf0 = Ks + w * 16384;
  unsigned char* buf1 = buf0 + 8192;

  // Q fragments: 32 rows x 256 hd fp8 (A-operand layout), 32 VGPRs
  long qf0[8], qf1[8];
#pragma unroll
  for (int kk = 0; kk < 8; kk++) {
    qf0[kk] = *(const long*)(Qbase + (size_t)(l15) * NQK + kk * 32 + lg * 8);
    qf1[kk] = *(const long*)(Qbase + (size_t)(16 + l15) * NQK + kk * 32 + lg * 8);
  }
  asm volatile("s_waitcnt vmcnt(0)" ::: "memory");   // drain Q so vmcnt counts are exact
  __builtin_amdgcn_sched_barrier(0);

  float z00 = 0.f, z01 = 0.f, z02 = 0.f, z03 = 0.f;
  float z10 = 0.f, z11 = 0.f, z12 = 0.f, z13 = 0.f;
  // E: exp(S) packed 4x e4m3 per u32; frag f (16 keys) x {a: rows m0, b: rows m1}
  unsigned E0a, E1a, E2a, E3a, E4a, E5a, E6a, E7a;
  unsigned E8a, E9a, E10a, E11a, E12a, E13a, E14a, E15a;
  unsigned E0b, E1b, E2b, E3b, E4b, E5b, E6b, E7b;
  unsigned E8b, E9b, E10b, E11b, E12b, E13b, E14b, E15b;
  int swz = (l15 & 7) << 4;
  const float SC = 0.09016844f;            // 0.0625 * log2(e): e^(s/16) == 2^(s*SC)

  // stage tile nn (32 keys x 256B = 8KB) into dst, XOR-swizzled via source
#define STAGE(nn, dst)                                                         \
  {                                                                            \
    _Pragma("unroll")                                                          \
    for (int i = 0; i < 8; i++) {                                              \
      int o = i * 1024 + lane * 16;                                            \
      int s = o >> 8;                                                          \
      int db = (o & 255) ^ ((s & 7) << 4);                                     \
      gl_lds16(Kbase + (size_t)((nn) * 32 + s) * NQK + db, (dst) + o);         \
    }                                                                          \
  }

#define PACK(acc, Z0, Z1, Z2, Z3, Edst)                                        \
  {                                                                            \
    float e0 = exp2f((acc)[0] * SC), e1 = exp2f((acc)[1] * SC);                \
    float e2 = exp2f((acc)[2] * SC), e3 = exp2f((acc)[3] * SC);                \
    Z0 += e0; Z1 += e1; Z2 += e2; Z3 += e3;                                    \
    unsigned u_ = __builtin_amdgcn_cvt_pk_fp8_f32(e0, e1, 0, false);           \
    Edst = __builtin_amdgcn_cvt_pk_fp8_f32(e2, e3, (int)u_, true);             \
  }

  // tile = 32 keys = 2 key-frags (g0: rows l15, g1: rows 16+l15)
#define TILE(n, EA0, EB0, EA1, EB1, cur, nxt, STG)                             \
  {                                                                            \
    if (STG) {                                                                 \
      STAGE((n) + 1, nxt);                                                     \
      asm volatile("s_waitcnt vmcnt(8)" ::: "memory");                         \
    } else {                                                                   \
      asm volatile("s_waitcnt vmcnt(0)" ::: "memory");                         \
    }                                                                          \
    __builtin_amdgcn_sched_barrier(0);                                         \
    f32x4 a00 = {}, a01 = {}, a10 = {}, a11 = {};                              \
    __builtin_amdgcn_s_setprio(1);                                             \
    _Pragma("unroll")                                                          \
    for (int kk = 0; kk < 8; kk++) {                                           \
      int co = (kk * 32 + lg * 8) ^ swz;                                       \
      long kf0 = *(const long*)((cur) + l15 * 256 + co);                       \
      long kf1 = *(const long*)((cur) + (16 + l15) * 256 + co);                \
      a00 = __builtin_amdgcn_mfma_f32_16x16x32_fp8_fp8(qf0[kk], kf0, a00, 0, 0, 0); \
      a01 = __builtin_amdgcn_mfma_f32_16x16x32_fp8_fp8(qf1[kk], kf0, a01, 0, 0, 0); \
      a10 = __builtin_amdgcn_mfma_f32_16x16x32_fp8_fp8(qf0[kk], kf1, a10, 0, 0, 0); \
      a11 = __builtin_amdgcn_mfma_f32_16x16x32_fp8_fp8(qf1[kk], kf1, a11, 0, 0, 0); \
    }                                                                          \
    __builtin_amdgcn_s_setprio(0);                                             \
    PACK(a00, z00, z01, z02, z03, EA0)                                         \
    PACK(a01, z10, z11, z12, z13, EB0)                                         \
    PACK(a10, z00, z01, z02, z03, EA1)                                         \
    PACK(a11, z10, z11, z12, z13, EB1)                                         \
  }

  STAGE(0, buf0);
  TILE(0, E0a,  E0b,  E1a,  E1b,  buf0, buf1, 1)
  TILE(1, E2a,  E2b,  E3a,  E3b,  buf1, buf0, 1)
  TILE(2, E4a,  E4b,  E5a,  E5b,  buf0, buf1, 1)
  TILE(3, E6a,  E6b,  E7a,  E7b,  buf1, buf0, 1)
  TILE(4, E8a,  E8b,  E9a,  E9b,  buf0, buf1, 1)
  TILE(5, E10a, E10b, E11a, E11b, buf1, buf0, 1)
  TILE(6, E12a, E12b, E13a, E13b, buf0, buf1, 1)
  TILE(7, E14a, E14b, E15a, E15b, buf1, buf0, 0)
#undef TILE
#undef PACK
#undef STAGE

  // ---- Z combine across the 8 key-strip waves ----
  __syncthreads();
  float* Zpf = (float*)Ks;                 // [8][32]
#define REDZ(zv, slot)                                                         \
  {                                                                            \
    float z = (zv);                                                            \
    z += __shfl_xor(z, 1, 64);                                                 \
    z += __shfl_xor(z, 2, 64);                                                 \
    z += __shfl_xor(z, 4, 64);                                                 \
    z += __shfl_xor(z, 8, 64);                                                 \
    if (l15 == 0) Zpf[w * 32 + (slot)] = z;                                    \
  }
  REDZ(z00, lg * 4 + 0)  REDZ(z01, lg * 4 + 1)
  REDZ(z02, lg * 4 + 2)  REDZ(z03, lg * 4 + 3)
  REDZ(z10, 16 + lg * 4 + 0)  REDZ(z11, 16 + lg * 4 + 1)
  REDZ(z12, 16 + lg * 4 + 2)  REDZ(z13, 16 + lg * 4 + 3)
#undef REDZ
  __syncthreads();

  float invz00, invz01, invz02, invz03, invz10, invz11, invz12, invz13;
  {
    f32x4 s0 = {}, s1 = {};
#pragma unroll
    for (int j = 0; j < 8; j++) {
      s0 += *(const f32x4*)(Zpf + j * 32 + lg * 4);
      s1 += *(const f32x4*)(Zpf + j * 32 + 16 + lg * 4);
    }
    invz00 = 1.0f / s0[0]; invz01 = 1.0f / s0[1];
    invz02 = 1.0f / s0[2]; invz03 = 1.0f / s0[3];
    invz10 = 1.0f / s1[0]; invz11 = 1.0f / s1[1];
    invz12 = 1.0f / s1[2]; invz13 = 1.0f / s1[3];
  }

  // ---- column sums straight from register-resident fp8 E; plain stores, no atomics ----
  float* myrow = buf + (size_t)hr * 8192 + b * 2048 + w * 256;
#define COL(f)                                                                 \
  {                                                                            \
    float c = 0.f;                                                             \
    c += __builtin_amdgcn_cvt_f32_fp8(E##f##a, 0) * invz00;                    \
    c += __builtin_amdgcn_cvt_f32_fp8(E##f##a, 1) * invz01;                    \
    c += __builtin_amdgcn_cvt_f32_fp8(E##f##a, 2) * invz02;                    \
    c += __builtin_amdgcn_cvt_f32_fp8(E##f##a, 3) * invz03;                    \
    c += __builtin_amdgcn_cvt_f32_fp8(E##f##b, 0) * invz10;                    \
    c += __builtin_amdgcn_cvt_f32_fp8(E##f##b, 1) * invz11;                    \
    c += __builtin_amdgcn_cvt_f32_fp8(E##f##b, 2) * invz12;                    \
    c += __builtin_amdgcn_cvt_f32_fp8(E##f##b, 3) * invz13;                    \
    c += __shfl_xor(c, 16, 64);                                                \
    c += __shfl_xor(c, 32, 64);                                                \
    if (lane < 16) myrow[(f) * 16 + l15] = c;                                  \
  }
  COL(0)  COL(1)  COL(2)  COL(3)  COL(4)  COL(5)  COL(6)  COL(7)
  COL(8)  COL(9)  COL(10) COL(11) COL(12) COL(13) COL(14) COL(15)
#undef COL
}

// ---------------- reduce partials: colsum[bs] = sum_hr buf[hr][bs] ----------------
__global__ __launch_bounds__(256) void reduce_kernel(
    const float* __restrict__ buf, float* __restrict__ colsum) {
  int bs = blockIdx.x * 256 + threadIdx.x;   // 0..8191
  float s = 0.f;
#pragma unroll 8
  for (int hr = 0; hr < 256; hr++) s += buf[(size_t)hr * 8192 + bs];
  colsum[bs] = s;
}

// ---------------- finalize ----------------
__global__ __launch_bounds__(256) void finalize_kernel(
    const float* __restrict__ colsum, float* __restrict__ out) {
  __shared__ float red[256];
  int t = threadIdx.x;
  float acc = 0.f;
  for (int i = t; i < NB * LSEQ; i += 256) {
    float aw = colsum[i] * (1.0f / 8192.0f) + 1e-8f;
    acc += -aw * __logf(aw);
  }
  red[t] = acc;
  __syncthreads();
  for (int s = 128; s > 0; s >>= 1) {
    if (t < s) red[t] += red[t + s];
    __syncthreads();
  }
  if (t == 0) {
    float me = red[0] * 0.25f;
    out[0] = 1.0f / (1.0f + __expf(-me));
  }
}

extern "C" void kernel_launch(void* const* d_in, const int* in_sizes, int n_in,
                              void* d_out, int out_size, void* d_ws, size_t ws_size,
                              hipStream_t stream) {
  const float* hs   = (const float*)d_in[0];   // [4,2048,1024]
  const float* wgt  = (const float*)d_in[1];   // [3072,1024]
  const float* bias = (const float*)d_in[2];   // [3072]
  float* out = (float*)d_out;
  char* ws = (char*)d_ws;

  unsigned short* Xb = (unsigned short*)(ws);                   // 16 MB
  unsigned short* Wb = (unsigned short*)(ws + (16u << 20));     // 4 MB
  unsigned char*  C8 = (unsigned char*)(ws + (20u << 20));      // 16 MB fp8
  float* colsum = (float*)(ws + (36u << 20));                   // 32 KB
  float* pbuf   = (float*)(ws + (40u << 20));                   // 8 MB partials

  cvt_kernel<<<(NX4 + NW4) / 256, 256, 0, stream>>>(
      (const float4*)hs, (const float4*)wgt, (ushort4*)Xb);

  gemm_qk<<<1024, 256, 0, stream>>>(Xb, Wb, bias, C8);

  attn_fused<<<1024, 512, 0, stream>>>(C8, pbuf);
  reduce_kernel<<<32, 256, 0, stream>>>(pbuf, colsum);
  finalize_kernel<<<1, 256, 0, stream>>>(colsum, out);
}

// Round 12
// 128.111 us; speedup vs baseline: 1.1910x; 1.1910x over previous
//
#include <hip/hip_runtime.h>

typedef __attribute__((ext_vector_type(4))) float f32x4;

#define D_MODEL 1024
#define NQK     2048
#define LSEQ    2048
#define NB      4
#define NXF16   524288    // 8192*1024/16
#define NTOT16  655360    // (8192*1024 + 2048*1024)/16

__device__ inline void gl_lds16(const void* g, void* l) {
  __builtin_amdgcn_global_load_lds((const __attribute__((address_space(1))) void*)g,
                                   (__attribute__((address_space(3))) void*)l, 16, 0, 0);
}

// ---------------- fp32 -> fp8 convert (X then W, contiguous dst) + colsum zeroing ----------------
__global__ __launch_bounds__(256) void cvt_zero_kernel(
    const float4* __restrict__ X, const float4* __restrict__ W,
    uint4* __restrict__ dst, float* __restrict__ colsum) {
  int i = blockIdx.x * 256 + threadIdx.x;          // one thread = 16 floats
  if (blockIdx.x < 32) colsum[i] = 0.f;            // zero colsum[8192]
  const float4* src = (i < NXF16) ? (X + (size_t)i * 4) : (W + (size_t)(i - NXF16) * 4);
  float4 v0 = src[0], v1 = src[1], v2 = src[2], v3 = src[3];
  unsigned u0 = __builtin_amdgcn_cvt_pk_fp8_f32(v0.x, v0.y, 0, false);
  u0 = __builtin_amdgcn_cvt_pk_fp8_f32(v0.z, v0.w, (int)u0, true);
  unsigned u1 = __builtin_amdgcn_cvt_pk_fp8_f32(v1.x, v1.y, 0, false);
  u1 = __builtin_amdgcn_cvt_pk_fp8_f32(v1.z, v1.w, (int)u1, true);
  unsigned u2 = __builtin_amdgcn_cvt_pk_fp8_f32(v2.x, v2.y, 0, false);
  u2 = __builtin_amdgcn_cvt_pk_fp8_f32(v2.z, v2.w, (int)u2, true);
  unsigned u3 = __builtin_amdgcn_cvt_pk_fp8_f32(v3.x, v3.y, 0, false);
  u3 = __builtin_amdgcn_cvt_pk_fp8_f32(v3.z, v3.w, (int)u3, true);
  uint4 o; o.x = u0; o.y = u1; o.z = u2; o.w = u3;
  dst[i] = o;
}

// ---------------- GEMM: Q,K = X W^T + bias, fp8 inputs, fp8 output ----------------
// 128x128 tile, 4 waves, BK=32 (32B fp8 rows: dense ds_read_b64, no swizzle needed).
// Bijective XCD swizzle: XCD x owns m-panels [8x,8x+8) x all 16 n-blocks (X panel 1MB +
// W 2MB L2-resident per XCD).
__global__ __launch_bounds__(256) void gemm_qk(
    const unsigned char* __restrict__ X8,    // [8192][1024] fp8
    const unsigned char* __restrict__ W8,    // [2048][1024] fp8
    const float* __restrict__ bias,          // [3072]
    unsigned char* __restrict__ C)           // [8192][2048] fp8 e4m3
{
  __shared__ unsigned char As[128 * 32];   // 4KB
  __shared__ unsigned char Bs[128 * 32];   // 4KB
  int t = threadIdx.x;
  int w = t >> 6, lane = t & 63;
  int l15 = lane & 15, lg = lane >> 4;
  int bid = blockIdx.x;
  int k2 = bid >> 3, xcd = bid & 7;
  int m0 = (xcd * 8 + (k2 >> 4)) * 128;
  int n0 = (k2 & 15) * 128;
  int wm = (w >> 1) * 64, wn = (w & 1) * 64;
  int srow = t >> 1, scol = (t & 1) * 16;  // staging: thread covers half a 32B row
  f32x4 acc[4][4] = {};

  for (int kt = 0; kt < 32; ++kt) {
    gl_lds16(X8 + (size_t)(m0 + srow) * D_MODEL + kt * 32 + scol, (char*)As + t * 16);
    gl_lds16(W8 + (size_t)(n0 + srow) * D_MODEL + kt * 32 + scol, (char*)Bs + t * 16);
    __syncthreads();
    long a[4], b[4];
#pragma unroll
    for (int mi = 0; mi < 4; mi++)
      a[mi] = *(const long*)(As + (wm + mi * 16 + l15) * 32 + lg * 8);
#pragma unroll
    for (int ni = 0; ni < 4; ni++)
      b[ni] = *(const long*)(Bs + (wn + ni * 16 + l15) * 32 + lg * 8);
#pragma unroll
    for (int mi = 0; mi < 4; mi++)
#pragma unroll
      for (int ni = 0; ni < 4; ni++)
        acc[mi][ni] = __builtin_amdgcn_mfma_f32_16x16x32_fp8_fp8(a[mi], b[ni], acc[mi][ni], 0, 0, 0);
    __syncthreads();
  }

#pragma unroll
  for (int ni = 0; ni < 4; ni++) {
    int n = n0 + wn + ni * 16 + l15;
    float bv = bias[n];
#pragma unroll
    for (int mi = 0; mi < 4; mi++) {
      int mbase = m0 + wm + mi * 16 + lg * 4;
#pragma unroll
      for (int r = 0; r < 4; r++) {
        float v = acc[mi][ni][r] + bv;
        unsigned u = __builtin_amdgcn_cvt_pk_fp8_f32(v, v, 0, false);
        C[(size_t)(mbase + r) * NQK + n] = (unsigned char)u;
      }
    }
  }
}

// ---------------- fused attention column sums (fp8, wave-private strips) ----------------
// EXACT round-10 structure (proven 67.5us, VGPR=96, no spill): wg = 512 threads (8 waves),
// all sharing 32 q-rows of one (b,h); wave w owns key strip [w*256,(w+1)*256), staged
// 32-keys (8KB) at a time into a wave-private double-buffered 2x8KB LDS slice (128KB =>
// 1 wg/CU => 2 waves/EU => 256-VGPR budget). Plain __launch_bounds__(512).
// Fully manually unrolled 8-tile pipeline, named E registers, counted vmcnt(8).
__global__ __launch_bounds__(512) void attn_fused(
    const unsigned char* __restrict__ C,   // [8192][2048] fp8
    float* __restrict__ colsum)            // [4][2048]
{
  __shared__ unsigned char Ks[131072];     // 8 waves x 2 bufs x 8KB
  int t = threadIdx.x;
  int w = t >> 6, lane = t & 63;
  int l15 = lane & 15, lg = lane >> 4;

  // XCD swizzle: 128 consecutive nids (2 bh) per XCD -> K slice L2-resident
  int nid = (blockIdx.x & 7) * 128 + (blockIdx.x >> 3);
  int bh = nid >> 6, rb = nid & 63;
  int b = bh >> 2, h = bh & 3;

  const unsigned char* Qbase = C + (size_t)(b * LSEQ + rb * 32) * NQK + h * 256;
  const unsigned char* Kbase = C + (size_t)(b * LSEQ + w * 256) * NQK + 1024 + h * 256;
  unsigned char* buf0 = Ks + w * 16384;
  unsigned char* buf1 = buf0 + 8192;

  // Q fragments: 32 rows x 256 hd fp8 (A-operand layout), 32 VGPRs
  long qf0[8], qf1[8];
#pragma unroll
  for (int kk = 0; kk < 8; kk++) {
    qf0[kk] = *(const long*)(Qbase + (size_t)(l15) * NQK + kk * 32 + lg * 8);
    qf1[kk] = *(const long*)(Qbase + (size_t)(16 + l15) * NQK + kk * 32 + lg * 8);
  }
  asm volatile("s_waitcnt vmcnt(0)" ::: "memory");   // drain Q so vmcnt counts are exact
  __builtin_amdgcn_sched_barrier(0);

  float z00 = 0.f, z01 = 0.f, z02 = 0.f, z03 = 0.f;
  float z10 = 0.f, z11 = 0.f, z12 = 0.f, z13 = 0.f;
  // E: exp(S) packed 4x e4m3 per u32; frag f (16 keys) x {a: rows m0, b: rows m1}
  unsigned E0a, E1a, E2a, E3a, E4a, E5a, E6a, E7a;
  unsigned E8a, E9a, E10a, E11a, E12a, E13a, E14a, E15a;
  unsigned E0b, E1b, E2b, E3b, E4b, E5b, E6b, E7b;
  unsigned E8b, E9b, E10b, E11b, E12b, E13b, E14b, E15b;
  int swz = (l15 & 7) << 4;

  // stage tile nn (32 keys x 256B = 8KB) into dst, XOR-swizzled via source
#define STAGE(nn, dst)                                                         \
  {                                                                            \
    _Pragma("unroll")                                                          \
    for (int i = 0; i < 8; i++) {                                              \
      int o = i * 1024 + lane * 16;                                            \
      int s = o >> 8;                                                          \
      int db = (o & 255) ^ ((s & 7) << 4);                                     \
      gl_lds16(Kbase + (size_t)((nn) * 32 + s) * NQK + db, (dst) + o);         \
    }                                                                          \
  }

#define PACK(acc, Z0, Z1, Z2, Z3, Edst)                                        \
  {                                                                            \
    float e0 = __expf((acc)[0] * 0.0625f), e1 = __expf((acc)[1] * 0.0625f);    \
    float e2 = __expf((acc)[2] * 0.0625f), e3 = __expf((acc)[3] * 0.0625f);    \
    Z0 += e0; Z1 += e1; Z2 += e2; Z3 += e3;                                    \
    unsigned u_ = __builtin_amdgcn_cvt_pk_fp8_f32(e0, e1, 0, false);           \
    Edst = __builtin_amdgcn_cvt_pk_fp8_f32(e2, e3, (int)u_, true);             \
  }

  // tile = 32 keys = 2 key-frags (g0: rows l15, g1: rows 16+l15)
#define TILE(n, EA0, EB0, EA1, EB1, cur, nxt, STG)                             \
  {                                                                            \
    if (STG) {                                                                 \
      STAGE((n) + 1, nxt);                                                     \
      asm volatile("s_waitcnt vmcnt(8)" ::: "memory");                         \
    } else {                                                                   \
      asm volatile("s_waitcnt vmcnt(0)" ::: "memory");                         \
    }                                                                          \
    __builtin_amdgcn_sched_barrier(0);                                         \
    f32x4 a00 = {}, a01 = {}, a10 = {}, a11 = {};                              \
    _Pragma("unroll")                                                          \
    for (int kk = 0; kk < 8; kk++) {                                           \
      int co = (kk * 32 + lg * 8) ^ swz;                                       \
      long kf0 = *(const long*)((cur) + l15 * 256 + co);                       \
      long kf1 = *(const long*)((cur) + (16 + l15) * 256 + co);                \
      a00 = __builtin_amdgcn_mfma_f32_16x16x32_fp8_fp8(qf0[kk], kf0, a00, 0, 0, 0); \
      a01 = __builtin_amdgcn_mfma_f32_16x16x32_fp8_fp8(qf1[kk], kf0, a01, 0, 0, 0); \
      a10 = __builtin_amdgcn_mfma_f32_16x16x32_fp8_fp8(qf0[kk], kf1, a10, 0, 0, 0); \
      a11 = __builtin_amdgcn_mfma_f32_16x16x32_fp8_fp8(qf1[kk], kf1, a11, 0, 0, 0); \
    }                                                                          \
    PACK(a00, z00, z01, z02, z03, EA0)                                         \
    PACK(a01, z10, z11, z12, z13, EB0)                                         \
    PACK(a10, z00, z01, z02, z03, EA1)                                         \
    PACK(a11, z10, z11, z12, z13, EB1)                                         \
  }

  STAGE(0, buf0);
  TILE(0, E0a,  E0b,  E1a,  E1b,  buf0, buf1, 1)
  TILE(1, E2a,  E2b,  E3a,  E3b,  buf1, buf0, 1)
  TILE(2, E4a,  E4b,  E5a,  E5b,  buf0, buf1, 1)
  TILE(3, E6a,  E6b,  E7a,  E7b,  buf1, buf0, 1)
  TILE(4, E8a,  E8b,  E9a,  E9b,  buf0, buf1, 1)
  TILE(5, E10a, E10b, E11a, E11b, buf1, buf0, 1)
  TILE(6, E12a, E12b, E13a, E13b, buf0, buf1, 1)
  TILE(7, E14a, E14b, E15a, E15b, buf1, buf0, 0)
#undef TILE
#undef PACK
#undef STAGE

  // ---- Z combine across the 8 key-strip waves ----
  __syncthreads();
  float* Zpf = (float*)Ks;                 // [8][32]
#define REDZ(zv, slot)                                                         \
  {                                                                            \
    float z = (zv);                                                            \
    z += __shfl_xor(z, 1, 64);                                                 \
    z += __shfl_xor(z, 2, 64);                                                 \
    z += __shfl_xor(z, 4, 64);                                                 \
    z += __shfl_xor(z, 8, 64);                                                 \
    if (l15 == 0) Zpf[w * 32 + (slot)] = z;                                    \
  }
  REDZ(z00, lg * 4 + 0)  REDZ(z01, lg * 4 + 1)
  REDZ(z02, lg * 4 + 2)  REDZ(z03, lg * 4 + 3)
  REDZ(z10, 16 + lg * 4 + 0)  REDZ(z11, 16 + lg * 4 + 1)
  REDZ(z12, 16 + lg * 4 + 2)  REDZ(z13, 16 + lg * 4 + 3)
#undef REDZ
  __syncthreads();

  float invz00, invz01, invz02, invz03, invz10, invz11, invz12, invz13;
  {
    f32x4 s0 = {}, s1 = {};
#pragma unroll
    for (int j = 0; j < 8; j++) {
      s0 += *(const f32x4*)(Zpf + j * 32 + lg * 4);
      s1 += *(const f32x4*)(Zpf + j * 32 + 16 + lg * 4);
    }
    invz00 = 1.0f / s0[0]; invz01 = 1.0f / s0[1];
    invz02 = 1.0f / s0[2]; invz03 = 1.0f / s0[3];
    invz10 = 1.0f / s1[0]; invz11 = 1.0f / s1[1];
    invz12 = 1.0f / s1[2]; invz13 = 1.0f / s1[3];
  }

  // ---- column sums straight from register-resident fp8 E ----
#define COL(f)                                                                 \
  {                                                                            \
    float c = 0.f;                                                             \
    c += __builtin_amdgcn_cvt_f32_fp8(E##f##a, 0) * invz00;                    \
    c += __builtin_amdgcn_cvt_f32_fp8(E##f##a, 1) * invz01;                    \
    c += __builtin_amdgcn_cvt_f32_fp8(E##f##a, 2) * invz02;                    \
    c += __builtin_amdgcn_cvt_f32_fp8(E##f##a, 3) * invz03;                    \
    c += __builtin_amdgcn_cvt_f32_fp8(E##f##b, 0) * invz10;                    \
    c += __builtin_amdgcn_cvt_f32_fp8(E##f##b, 1) * invz11;                    \
    c += __builtin_amdgcn_cvt_f32_fp8(E##f##b, 2) * invz12;                    \
    c += __builtin_amdgcn_cvt_f32_fp8(E##f##b, 3) * invz13;                    \
    c += __shfl_xor(c, 16, 64);                                                \
    c += __shfl_xor(c, 32, 64);                                                \
    if (lane < 16)                                                             \
      atomicAdd(&colsum[b * LSEQ + w * 256 + (f) * 16 + l15], c);              \
  }
  COL(0)  COL(1)  COL(2)  COL(3)  COL(4)  COL(5)  COL(6)  COL(7)
  COL(8)  COL(9)  COL(10) COL(11) COL(12) COL(13) COL(14) COL(15)
#undef COL
}

// ---------------- finalize ----------------
__global__ __launch_bounds__(256) void finalize_kernel(
    const float* __restrict__ colsum, float* __restrict__ out) {
  __shared__ float red[256];
  int t = threadIdx.x;
  float acc = 0.f;
  for (int i = t; i < NB * LSEQ; i += 256) {
    float aw = colsum[i] * (1.0f / 8192.0f) + 1e-8f;
    acc += -aw * __logf(aw);
  }
  red[t] = acc;
  __syncthreads();
  for (int s = 128; s > 0; s >>= 1) {
    if (t < s) red[t] += red[t + s];
    __syncthreads();
  }
  if (t == 0) {
    float me = red[0] * 0.25f;
    out[0] = 1.0f / (1.0f + __expf(-me));
  }
}

extern "C" void kernel_launch(void* const* d_in, const int* in_sizes, int n_in,
                              void* d_out, int out_size, void* d_ws, size_t ws_size,
                              hipStream_t stream) {
  const float* hs   = (const float*)d_in[0];   // [4,2048,1024]
  const float* wgt  = (const float*)d_in[1];   // [3072,1024]
  const float* bias = (const float*)d_in[2];   // [3072]
  float* out = (float*)d_out;
  char* ws = (char*)d_ws;

  unsigned char* X8 = (unsigned char*)(ws);                     // 8 MB (X fp8, then W fp8 contiguous)
  unsigned char* W8 = (unsigned char*)(ws + (8u << 20));        // 2 MB
  unsigned char* C8 = (unsigned char*)(ws + (10u << 20));       // 16 MB fp8
  float* colsum = (float*)(ws + (26u << 20));                   // 32 KB

  cvt_zero_kernel<<<NTOT16 / 256, 256, 0, stream>>>(
      (const float4*)hs, (const float4*)wgt, (uint4*)X8, colsum);

  gemm_qk<<<1024, 256, 0, stream>>>(X8, W8, bias, C8);

  attn_fused<<<1024, 512, 0, stream>>>(C8, colsum);
  finalize_kernel<<<1, 256, 0, stream>>>(colsum, out);
}